// Round 11
// baseline (62.382 us; speedup 1.0000x reference)
//
#include <hip/hip_runtime.h>
#include <hip/hip_bf16.h>
#include <math.h>

#define B_N 4096
#define D_N 1024
#define K_N 256
#define BK 32                 // k per MFMA step
#define NSTEP (D_N / BK)      // 32

typedef __attribute__((ext_vector_type(8))) short bf16x8;           // 4 VGPR
typedef __attribute__((ext_vector_type(8))) unsigned short u16x8;   // 4 VGPR
typedef __attribute__((ext_vector_type(4))) float f32x4;            // MFMA C/D

static constexpr float K_EPS = 1e-8f;

static __device__ __forceinline__ unsigned short f32_to_bf16_rne(float f) {
    unsigned x = __builtin_bit_cast(unsigned, f);
    unsigned r = (x + 0x7FFFu + ((x >> 16) & 1u)) >> 16;
    return (unsigned short)r;
}
static __device__ __forceinline__ float bf16_bits_to_f32(unsigned short h) {
    unsigned x = ((unsigned)h) << 16;
    return __builtin_bit_cast(float, x);
}

// ---------------------------------------------------------------------------
// Kernel 1: centroid normalize + bf16 hi/lo split. grid = 256 x 256.
// ---------------------------------------------------------------------------
__global__ __launch_bounds__(256) void kcent_kernel(
    const float* __restrict__ cent,
    ushort* __restrict__ chi, ushort* __restrict__ clo)
{
    int row = blockIdx.x;
    int tid = threadIdx.x;
    float4 v = reinterpret_cast<const float4*>(cent + (size_t)row * D_N)[tid];
    float s = v.x * v.x + v.y * v.y + v.z * v.z + v.w * v.w;
    #pragma unroll
    for (int o = 32; o > 0; o >>= 1) s += __shfl_down(s, o);
    __shared__ float red[4];
    __shared__ float s_inv;
    if ((tid & 63) == 0) red[tid >> 6] = s;
    __syncthreads();
    if (tid == 0) {
        float t = red[0] + red[1] + red[2] + red[3];
        s_inv = 1.0f / fmaxf(sqrtf(t), K_EPS);
    }
    __syncthreads();
    float inv = s_inv;
    float e[4] = {v.x * inv, v.y * inv, v.z * inv, v.w * inv};
    ushort h4[4], l4[4];
    #pragma unroll
    for (int j = 0; j < 4; ++j) {
        ushort h = f32_to_bf16_rne(e[j]);
        float lo = e[j] - bf16_bits_to_f32(h);
        h4[j] = h;
        l4[j] = f32_to_bf16_rne(lo);
    }
    *reinterpret_cast<ushort4*>(chi + (size_t)row * D_N + tid * 4) =
        make_ushort4(h4[0], h4[1], h4[2], h4[3]);
    *reinterpret_cast<ushort4*>(clo + (size_t)row * D_N + tid * 4) =
        make_ushort4(l4[0], l4[1], l4[2], l4[3]);
}

// ---------------------------------------------------------------------------
// Kernel 2 (main): fused dp-normalize + split-MFMA GEMM + top-2 + gathers.
// grid = 256 blocks x 512 threads (8 waves), 2 blocks/CU (80KB LDS).
// R11 changes vs R10 (register-pressure + latency targeted):
//  - Stage 1 two-pass (sumsq pass, then reload+convert pass; a "memory"
//    clobber between forces the reload so only ~8 VGPRs stay live).
//  - B prefetch depth 4 (distance ~460 cyc >> L2 latency ~225), issued
//    after the stage-1 barrier; 4 per-wave base pointers + imm offsets.
// ---------------------------------------------------------------------------
__global__ __launch_bounds__(512, 4) void kmain_kernel(
    const float* __restrict__ dp, const float* __restrict__ cent,
    const ushort* __restrict__ chi, const ushort* __restrict__ clo,
    float* __restrict__ out_sims, float* __restrict__ out_dpidx,
    float* __restrict__ out_hnidx, float* __restrict__ out_top1,
    float* __restrict__ out_dpcent, float* __restrict__ out_hneg,
    int* __restrict__ ws_dpidx)
{
    __shared__ ushort AhL[16 * 1024];   // 32 KB (swizzled)
    __shared__ ushort AlL[16 * 1024];   // 32 KB
    __shared__ float  simsL[16 * 256];  // 16 KB
    int tid  = threadIdx.x;
    int lane = tid & 63;
    int w    = tid >> 6;        // wave 0..7
    int lr   = lane & 15;
    int lg   = lane >> 4;
    int brow = blockIdx.x * 16;

    // ---- Stage 1: fused dp normalization (two-pass, low register) ----
    {
        int grp = tid & 31;          // 32 threads per row
        int row = tid >> 5;          // 0..15
        const float4* r4 = reinterpret_cast<const float4*>(
            dp + (size_t)(brow + row) * D_N);
        float s = 0.f;
        #pragma unroll
        for (int q = 0; q < 4; ++q) {
            float4 a = r4[grp * 2 + q * 64];
            float4 b = r4[grp * 2 + 1 + q * 64];
            s += a.x*a.x + a.y*a.y + a.z*a.z + a.w*a.w;
            s += b.x*b.x + b.y*b.y + b.z*b.z + b.w*b.w;
        }
        #pragma unroll
        for (int o = 1; o < 32; o <<= 1) s += __shfl_xor(s, o);
        float inv = 1.0f / fmaxf(sqrtf(s), K_EPS);
        asm volatile("" ::: "memory");   // force pass-2 reload (no CSE)
        #pragma unroll
        for (int q = 0; q < 4; ++q) {
            float4 a = r4[grp * 2 + q * 64];
            float4 b = r4[grp * 2 + 1 + q * 64];
            float e0 = a.x*inv, e1 = a.y*inv, e2 = a.z*inv, e3 = a.w*inv;
            float e4 = b.x*inv, e5 = b.y*inv, e6 = b.z*inv, e7 = b.w*inv;
            ushort h0=f32_to_bf16_rne(e0), h1=f32_to_bf16_rne(e1),
                   h2=f32_to_bf16_rne(e2), h3=f32_to_bf16_rne(e3),
                   h4=f32_to_bf16_rne(e4), h5=f32_to_bf16_rne(e5),
                   h6=f32_to_bf16_rne(e6), h7=f32_to_bf16_rne(e7);
            u16x8 hv = {h0,h1,h2,h3,h4,h5,h6,h7};
            u16x8 lv = {f32_to_bf16_rne(e0 - bf16_bits_to_f32(h0)),
                        f32_to_bf16_rne(e1 - bf16_bits_to_f32(h1)),
                        f32_to_bf16_rne(e2 - bf16_bits_to_f32(h2)),
                        f32_to_bf16_rne(e3 - bf16_bits_to_f32(h3)),
                        f32_to_bf16_rne(e4 - bf16_bits_to_f32(h4)),
                        f32_to_bf16_rne(e5 - bf16_bits_to_f32(h5)),
                        f32_to_bf16_rne(e6 - bf16_bits_to_f32(h6)),
                        f32_to_bf16_rne(e7 - bf16_bits_to_f32(h7))};
            int slot = (q * 32 + grp) ^ (row & 7);
            *reinterpret_cast<u16x8*>(&AhL[row * 1024 + slot * 8]) = hv;
            *reinterpret_cast<u16x8*>(&AlL[row * 1024 + slot * 8]) = lv;
        }
    }
    __syncthreads();

    // ---- Stage 2: K-loop, depth-4 register prefetch, no barriers ----
    // per-wave base pointers; per-step offset = t*BK elems = t*64 B (imm-foldable)
    const ushort* bh0 = chi + (size_t)((w * 2 + 0) * 16 + lr) * D_N + lg * 8;
    const ushort* bl0 = clo + (size_t)((w * 2 + 0) * 16 + lr) * D_N + lg * 8;
    const ushort* bh1 = chi + (size_t)((w * 2 + 1) * 16 + lr) * D_N + lg * 8;
    const ushort* bl1 = clo + (size_t)((w * 2 + 1) * 16 + lr) * D_N + lg * 8;

    f32x4 acc[2] = {};
    const char* AhC = (const char*)AhL;
    const char* AlC = (const char*)AlL;

    auto step = [&](int t, bf16x8 h0, bf16x8 l0, bf16x8 h1, bf16x8 l1) {
        int g = 4 * t + lg;                      // global 16B chunk in row
        unsigned ca = (unsigned)(g ^ (lr & 7));  // swizzled slot
        unsigned ao = (unsigned)lr * 2048u + ca * 16u;
        bf16x8 ah = *reinterpret_cast<const bf16x8*>(AhC + ao);
        bf16x8 al = *reinterpret_cast<const bf16x8*>(AlC + ao);
        acc[0] = __builtin_amdgcn_mfma_f32_16x16x32_bf16(ah, h0, acc[0], 0, 0, 0);
        acc[0] = __builtin_amdgcn_mfma_f32_16x16x32_bf16(ah, l0, acc[0], 0, 0, 0);
        acc[0] = __builtin_amdgcn_mfma_f32_16x16x32_bf16(al, h0, acc[0], 0, 0, 0);
        acc[1] = __builtin_amdgcn_mfma_f32_16x16x32_bf16(ah, h1, acc[1], 0, 0, 0);
        acc[1] = __builtin_amdgcn_mfma_f32_16x16x32_bf16(ah, l1, acc[1], 0, 0, 0);
        acc[1] = __builtin_amdgcn_mfma_f32_16x16x32_bf16(al, h1, acc[1], 0, 0, 0);
    };

    #define LB(t, H0, L0, H1, L1)                                        \
        H0 = *reinterpret_cast<const bf16x8*>(bh0 + (t) * BK);           \
        L0 = *reinterpret_cast<const bf16x8*>(bl0 + (t) * BK);           \
        H1 = *reinterpret_cast<const bf16x8*>(bh1 + (t) * BK);           \
        L1 = *reinterpret_cast<const bf16x8*>(bl1 + (t) * BK);

    bf16x8 ah0,al0,ah1,al1, bh0r,bl0r,bh1r,bl1r,
           ch0,cl0,ch1,cl1, dh0,dl0,dh1,dl1;
    LB(0, ah0, al0, ah1, al1)
    LB(1, bh0r, bl0r, bh1r, bl1r)
    LB(2, ch0, cl0, ch1, cl1)
    LB(3, dh0, dl0, dh1, dl1)
    #pragma unroll 1
    for (int t = 0; t < NSTEP; t += 4) {
        step(t + 0, ah0, al0, ah1, al1);
        if (t + 4 < NSTEP) { LB(t + 4, ah0, al0, ah1, al1) }
        step(t + 1, bh0r, bl0r, bh1r, bl1r);
        if (t + 5 < NSTEP) { LB(t + 5, bh0r, bl0r, bh1r, bl1r) }
        step(t + 2, ch0, cl0, ch1, cl1);
        if (t + 6 < NSTEP) { LB(t + 6, ch0, cl0, ch1, cl1) }
        step(t + 3, dh0, dl0, dh1, dl1);
        if (t + 7 < NSTEP) { LB(t + 7, dh0, dl0, dh1, dl1) }
    }
    #undef LB

    // ---- Stage 3: sims + fused top-2 + gathers ----
    // D layout: col = lane&15, row = (lane>>4)*4 + reg (m89-verified)
    #pragma unroll
    for (int tt = 0; tt < 2; ++tt)
        #pragma unroll
        for (int r = 0; r < 4; ++r) {
            int rl = lg * 4 + r;
            int cl = (w * 2 + tt) * 16 + lr;
            out_sims[(size_t)(brow + rl) * K_N + cl] = acc[tt][r];
            simsL[rl * K_N + cl] = acc[tt][r];
        }
    __syncthreads();

    const float4* cent4 = reinterpret_cast<const float4*>(cent);
    #pragma unroll
    for (int rloc = 0; rloc < 2; ++rloc) {
        int row_l = w * 2 + rloc;
        float4 c = *reinterpret_cast<const float4*>(&simsL[row_l * K_N + lane * 4]);
        float v1b = c.x; int i1 = lane * 4;
        float v2b = -INFINITY; int i2 = 0;
        {
            float vals[3] = {c.y, c.z, c.w};
            #pragma unroll
            for (int j = 0; j < 3; ++j) {
                float val = vals[j]; int idx = lane * 4 + j + 1;
                if (val > v1b) { v2b = v1b; i2 = i1; v1b = val; i1 = idx; }
                else if (val > v2b) { v2b = val; i2 = idx; }
            }
        }
        #pragma unroll
        for (int o = 1; o < 64; o <<= 1) {
            float ov1 = __shfl_xor(v1b, o);
            float ov2 = __shfl_xor(v2b, o);
            int   oi1 = __shfl_xor(i1, o);
            int   oi2 = __shfl_xor(i2, o);
            if (ov1 > v1b || (ov1 == v1b && oi1 < i1)) {
                float nv2; int ni2;
                if (v1b > ov2 || (v1b == ov2 && i1 < oi2)) { nv2 = v1b; ni2 = i1; }
                else { nv2 = ov2; ni2 = oi2; }
                v1b = ov1; i1 = oi1; v2b = nv2; i2 = ni2;
            } else if (ov1 > v2b || (ov1 == v2b && oi1 < i2)) {
                v2b = ov1; i2 = oi1;
            }
        }
        int row = brow + row_l;
        #pragma unroll
        for (int q = 0; q < 4; ++q) {
            float4 g1 = cent4[(size_t)i1 * 256 + q * 64 + lane];
            float4 g2 = cent4[(size_t)i2 * 256 + q * 64 + lane];
            reinterpret_cast<float4*>(out_dpcent + (size_t)row * D_N)[q * 64 + lane] = g1;
            reinterpret_cast<float4*>(out_hneg   + (size_t)row * D_N)[q * 64 + lane] = g2;
        }
        if (lane == 0) {
            out_dpidx[row] = (float)i1;
            out_hnidx[row] = (float)i2;
            out_top1[row]  = v2b;
            ws_dpidx[row]  = i1;
        }
    }
}

// ---------------------------------------------------------------------------
// Kernel 3: dp_cluster (B x B) + index_dp (K x B). grid = B_N + K_N blocks;
// fully coalesced float4 stores (1 KB/wave-instr).
// ---------------------------------------------------------------------------
__global__ __launch_bounds__(256) void kclust_kernel(
    const int* __restrict__ dpidx,
    float* __restrict__ out_cluster, float* __restrict__ out_indexdp)
{
    int bid = blockIdx.x;
    int tid = threadIdx.x;
    const int4* dpi4 = reinterpret_cast<const int4*>(dpidx);
    if (bid < B_N) {
        int i = bid;
        int me = dpidx[i];
        float* dst = out_cluster + (size_t)i * B_N;
        #pragma unroll
        for (int q = 0; q < 4; ++q) {
            int j = q * 1024 + tid * 4;
            int4 ix = dpi4[j >> 2];
            float4 v;
            v.x = (ix.x == me && (j + 0) != i) ? 1.0f : 0.0f;
            v.y = (ix.y == me && (j + 1) != i) ? 1.0f : 0.0f;
            v.z = (ix.z == me && (j + 2) != i) ? 1.0f : 0.0f;
            v.w = (ix.w == me && (j + 3) != i) ? 1.0f : 0.0f;
            *reinterpret_cast<float4*>(dst + j) = v;
        }
    } else {
        int k = bid - B_N;
        float* dst = out_indexdp + (size_t)k * B_N;
        #pragma unroll
        for (int q = 0; q < 4; ++q) {
            int j = q * 1024 + tid * 4;
            int4 ix = dpi4[j >> 2];
            float4 v;
            v.x = (ix.x == k) ? 1.0f : 0.0f;
            v.y = (ix.y == k) ? 1.0f : 0.0f;
            v.z = (ix.z == k) ? 1.0f : 0.0f;
            v.w = (ix.w == k) ? 1.0f : 0.0f;
            *reinterpret_cast<float4*>(dst + j) = v;
        }
    }
}

extern "C" void kernel_launch(void* const* d_in, const int* in_sizes, int n_in,
                              void* d_out, int out_size, void* d_ws, size_t ws_size,
                              hipStream_t stream)
{
    const float* dp   = (const float*)d_in[0];   // 4096 x 1024 f32
    const float* cent = (const float*)d_in[1];   // 256 x 1024 f32
    // d_in[2] (batch_cos_sim) is unused by the reference outputs.
    float* out = (float*)d_out;

    float* o_sims   = out;                 // 4096*256
    float* o_dpidx  = out + 1048576;       // 4096
    float* o_clust  = out + 1052672;       // 4096*4096
    float* o_idxdp  = out + 17829888;      // 256*4096
    float* o_dpcent = out + 18878464;      // 4096*1024
    float* o_hneg   = out + 23072768;      // 4096*1024
    float* o_hnidx  = out + 27267072;      // 4096
    float* o_top1   = out + 27271168;      // 4096

    char* ws = (char*)d_ws;
    ushort* chi  = (ushort*)ws;                         // 512 KiB
    ushort* clo  = (ushort*)(ws + (512u << 10));        // 512 KiB
    int*    widx = (int*)(ws + (1u << 20));             // 16 KiB

    hipLaunchKernelGGL(kcent_kernel, dim3(K_N), dim3(256), 0, stream,
                       cent, chi, clo);
    hipLaunchKernelGGL(kmain_kernel, dim3(B_N / 16), dim3(512), 0, stream,
                       dp, cent, chi, clo,
                       o_sims, o_dpidx, o_hnidx, o_top1,
                       o_dpcent, o_hneg, widx);
    hipLaunchKernelGGL(kclust_kernel, dim3(B_N + K_N), dim3(256), 0, stream,
                       widx, o_clust, o_idxdp);
}

// Round 12
// 44.493 us; speedup vs baseline: 1.4020x; 1.4020x over previous
//
#include <hip/hip_runtime.h>
#include <hip/hip_bf16.h>
#include <math.h>

#define B_N 4096
#define D_N 1024
#define K_N 256
#define BK 32                 // k per MFMA step
#define NSTEP (D_N / BK)      // 32

typedef __attribute__((ext_vector_type(8))) short bf16x8;           // 4 VGPR
typedef __attribute__((ext_vector_type(8))) unsigned short u16x8;   // 4 VGPR
typedef __attribute__((ext_vector_type(4))) float f32x4;            // MFMA C/D

static constexpr float K_EPS = 1e-8f;

static __device__ __forceinline__ unsigned short f32_to_bf16_rne(float f) {
    unsigned x = __builtin_bit_cast(unsigned, f);
    unsigned r = (x + 0x7FFFu + ((x >> 16) & 1u)) >> 16;
    return (unsigned short)r;
}
static __device__ __forceinline__ float bf16_bits_to_f32(unsigned short h) {
    unsigned x = ((unsigned)h) << 16;
    return __builtin_bit_cast(float, x);
}

// ---------------------------------------------------------------------------
// Kernel 1: centroid normalize + bf16 hi/lo split, written in PACKED
// MFMA-fragment order: chunk[(nt*32 + t)*64 + lg*16 + lr] (8 elems) =
// cn[(nt*16+lr)][t*32 + lg*8 .. +8].  So kmain's per-step wave load of a
// B-fragment is one CONTIGUOUS 1KB request instead of a 64-line gather.
// grid = 256 x 256.
// ---------------------------------------------------------------------------
__global__ __launch_bounds__(256) void kcent_kernel(
    const float* __restrict__ cent,
    ushort* __restrict__ phi, ushort* __restrict__ plo)
{
    int n   = blockIdx.x;
    int tid = threadIdx.x;
    float4 v = reinterpret_cast<const float4*>(cent + (size_t)n * D_N)[tid];
    float s = v.x * v.x + v.y * v.y + v.z * v.z + v.w * v.w;
    #pragma unroll
    for (int o = 32; o > 0; o >>= 1) s += __shfl_down(s, o);
    __shared__ float red[4];
    __shared__ float s_inv;
    if ((tid & 63) == 0) red[tid >> 6] = s;
    __syncthreads();
    if (tid == 0) {
        float t = red[0] + red[1] + red[2] + red[3];
        s_inv = 1.0f / fmaxf(sqrtf(t), K_EPS);
    }
    __syncthreads();
    float inv = s_inv;
    float e[4] = {v.x * inv, v.y * inv, v.z * inv, v.w * inv};
    ushort h4[4], l4[4];
    #pragma unroll
    for (int j = 0; j < 4; ++j) {
        ushort h = f32_to_bf16_rne(e[j]);
        float lo = e[j] - bf16_bits_to_f32(h);
        h4[j] = h;
        l4[j] = f32_to_bf16_rne(lo);
    }
    // packed destination: this thread covers k = tid*4 .. tid*4+3
    int nt = n >> 4, lr = n & 15;
    int k8 = tid >> 1, half = tid & 1;
    int t  = k8 >> 2, lg = k8 & 3;
    size_t chunk = (size_t)(nt * 32 + t) * 64 + lg * 16 + lr;
    *reinterpret_cast<ushort4*>(phi + chunk * 8 + half * 4) =
        make_ushort4(h4[0], h4[1], h4[2], h4[3]);
    *reinterpret_cast<ushort4*>(plo + chunk * 8 + half * 4) =
        make_ushort4(l4[0], l4[1], l4[2], l4[3]);
}

// ---------------------------------------------------------------------------
// Kernel 2 (main): fused dp-normalize + split-MFMA GEMM + top-2 + gathers.
// grid = 256 blocks x 512 threads (8 waves). Identical to R11 except:
//  - B frags come from the packed phi/plo layout: per step each wave issues
//    4 contiguous 1KB loads (base + t*1024B), depth-4 register rotation.
//  - sims written coalesced from simsL in the epilogue (was scattered 4B).
// ---------------------------------------------------------------------------
__global__ __launch_bounds__(512, 4) void kmain_kernel(
    const float* __restrict__ dp, const float* __restrict__ cent,
    const ushort* __restrict__ phi, const ushort* __restrict__ plo,
    float* __restrict__ out_sims, float* __restrict__ out_dpidx,
    float* __restrict__ out_hnidx, float* __restrict__ out_top1,
    float* __restrict__ out_dpcent, float* __restrict__ out_hneg,
    int* __restrict__ ws_dpidx)
{
    __shared__ ushort AhL[16 * 1024];   // 32 KB (swizzled)
    __shared__ ushort AlL[16 * 1024];   // 32 KB
    __shared__ float  simsL[16 * 256];  // 16 KB
    int tid  = threadIdx.x;
    int lane = tid & 63;
    int w    = tid >> 6;        // wave 0..7
    int lr   = lane & 15;
    int lg   = lane >> 4;
    int brow = blockIdx.x * 16;

    // ---- Stage 1: fused dp normalization (two-pass, low register) ----
    {
        int grp = tid & 31;          // 32 threads per row
        int row = tid >> 5;          // 0..15
        const float4* r4 = reinterpret_cast<const float4*>(
            dp + (size_t)(brow + row) * D_N);
        float s = 0.f;
        #pragma unroll
        for (int q = 0; q < 4; ++q) {
            float4 a = r4[grp * 2 + q * 64];
            float4 b = r4[grp * 2 + 1 + q * 64];
            s += a.x*a.x + a.y*a.y + a.z*a.z + a.w*a.w;
            s += b.x*b.x + b.y*b.y + b.z*b.z + b.w*b.w;
        }
        #pragma unroll
        for (int o = 1; o < 32; o <<= 1) s += __shfl_xor(s, o);
        float inv = 1.0f / fmaxf(sqrtf(s), K_EPS);
        asm volatile("" ::: "memory");   // force pass-2 reload (no CSE)
        #pragma unroll
        for (int q = 0; q < 4; ++q) {
            float4 a = r4[grp * 2 + q * 64];
            float4 b = r4[grp * 2 + 1 + q * 64];
            float e0 = a.x*inv, e1 = a.y*inv, e2 = a.z*inv, e3 = a.w*inv;
            float e4 = b.x*inv, e5 = b.y*inv, e6 = b.z*inv, e7 = b.w*inv;
            ushort h0=f32_to_bf16_rne(e0), h1=f32_to_bf16_rne(e1),
                   h2=f32_to_bf16_rne(e2), h3=f32_to_bf16_rne(e3),
                   h4=f32_to_bf16_rne(e4), h5=f32_to_bf16_rne(e5),
                   h6=f32_to_bf16_rne(e6), h7=f32_to_bf16_rne(e7);
            u16x8 hv = {h0,h1,h2,h3,h4,h5,h6,h7};
            u16x8 lv = {f32_to_bf16_rne(e0 - bf16_bits_to_f32(h0)),
                        f32_to_bf16_rne(e1 - bf16_bits_to_f32(h1)),
                        f32_to_bf16_rne(e2 - bf16_bits_to_f32(h2)),
                        f32_to_bf16_rne(e3 - bf16_bits_to_f32(h3)),
                        f32_to_bf16_rne(e4 - bf16_bits_to_f32(h4)),
                        f32_to_bf16_rne(e5 - bf16_bits_to_f32(h5)),
                        f32_to_bf16_rne(e6 - bf16_bits_to_f32(h6)),
                        f32_to_bf16_rne(e7 - bf16_bits_to_f32(h7))};
            int slot = (q * 32 + grp) ^ (row & 7);
            *reinterpret_cast<u16x8*>(&AhL[row * 1024 + slot * 8]) = hv;
            *reinterpret_cast<u16x8*>(&AlL[row * 1024 + slot * 8]) = lv;
        }
    }
    __syncthreads();

    // ---- Stage 2: K-loop, packed-B contiguous loads, depth-4 rotation ----
    // wave w owns n-tiles nt0 = 2w, nt1 = 2w+1.
    // packed: frag(nt, t) = 64 chunks of 8 elems at (nt*32 + t)*512.
    const ushort* bh0 = phi + (size_t)w * 32768 + lane * 8;   // nt0, t=0
    const ushort* bl0 = plo + (size_t)w * 32768 + lane * 8;
    const ushort* bh1 = bh0 + 16384;                          // nt1
    const ushort* bl1 = bl0 + 16384;

    f32x4 acc[2] = {};
    const char* AhC = (const char*)AhL;
    const char* AlC = (const char*)AlL;

    auto step = [&](int t, bf16x8 h0, bf16x8 l0, bf16x8 h1, bf16x8 l1) {
        int g = 4 * t + lg;                      // global 16B chunk in row
        unsigned ca = (unsigned)(g ^ (lr & 7));  // swizzled slot
        unsigned ao = (unsigned)lr * 2048u + ca * 16u;
        bf16x8 ah = *reinterpret_cast<const bf16x8*>(AhC + ao);
        bf16x8 al = *reinterpret_cast<const bf16x8*>(AlC + ao);
        acc[0] = __builtin_amdgcn_mfma_f32_16x16x32_bf16(ah, h0, acc[0], 0, 0, 0);
        acc[0] = __builtin_amdgcn_mfma_f32_16x16x32_bf16(ah, l0, acc[0], 0, 0, 0);
        acc[0] = __builtin_amdgcn_mfma_f32_16x16x32_bf16(al, h0, acc[0], 0, 0, 0);
        acc[1] = __builtin_amdgcn_mfma_f32_16x16x32_bf16(ah, h1, acc[1], 0, 0, 0);
        acc[1] = __builtin_amdgcn_mfma_f32_16x16x32_bf16(ah, l1, acc[1], 0, 0, 0);
        acc[1] = __builtin_amdgcn_mfma_f32_16x16x32_bf16(al, h1, acc[1], 0, 0, 0);
    };

    #define LB(t, H0, L0, H1, L1)                                        \
        H0 = *reinterpret_cast<const bf16x8*>(bh0 + (t) * 512);          \
        L0 = *reinterpret_cast<const bf16x8*>(bl0 + (t) * 512);          \
        H1 = *reinterpret_cast<const bf16x8*>(bh1 + (t) * 512);          \
        L1 = *reinterpret_cast<const bf16x8*>(bl1 + (t) * 512);

    bf16x8 ah0,al0,ah1,al1, bh0r,bl0r,bh1r,bl1r,
           ch0,cl0,ch1,cl1, dh0,dl0,dh1,dl1;
    LB(0, ah0, al0, ah1, al1)
    LB(1, bh0r, bl0r, bh1r, bl1r)
    LB(2, ch0, cl0, ch1, cl1)
    LB(3, dh0, dl0, dh1, dl1)
    #pragma unroll 1
    for (int t = 0; t < NSTEP; t += 4) {
        step(t + 0, ah0, al0, ah1, al1);
        if (t + 4 < NSTEP) { LB(t + 4, ah0, al0, ah1, al1) }
        step(t + 1, bh0r, bl0r, bh1r, bl1r);
        if (t + 5 < NSTEP) { LB(t + 5, bh0r, bl0r, bh1r, bl1r) }
        step(t + 2, ch0, cl0, ch1, cl1);
        if (t + 6 < NSTEP) { LB(t + 6, ch0, cl0, ch1, cl1) }
        step(t + 3, dh0, dl0, dh1, dl1);
        if (t + 7 < NSTEP) { LB(t + 7, dh0, dl0, dh1, dl1) }
    }
    #undef LB

    // ---- Stage 3: simsL + fused top-2 + coalesced sims write + gathers ----
    // D layout: col = lane&15, row = (lane>>4)*4 + reg (m89-verified)
    #pragma unroll
    for (int tt = 0; tt < 2; ++tt)
        #pragma unroll
        for (int r = 0; r < 4; ++r)
            simsL[(lg * 4 + r) * K_N + (w * 2 + tt) * 16 + lr] = acc[tt][r];
    __syncthreads();

    const float4* cent4 = reinterpret_cast<const float4*>(cent);
    #pragma unroll
    for (int rloc = 0; rloc < 2; ++rloc) {
        int row_l = w * 2 + rloc;
        int row   = brow + row_l;
        float4 c = *reinterpret_cast<const float4*>(&simsL[row_l * K_N + lane * 4]);
        *reinterpret_cast<float4*>(&out_sims[(size_t)row * K_N + lane * 4]) = c;
        float v1b = c.x; int i1 = lane * 4;
        float v2b = -INFINITY; int i2 = 0;
        {
            float vals[3] = {c.y, c.z, c.w};
            #pragma unroll
            for (int j = 0; j < 3; ++j) {
                float val = vals[j]; int idx = lane * 4 + j + 1;
                if (val > v1b) { v2b = v1b; i2 = i1; v1b = val; i1 = idx; }
                else if (val > v2b) { v2b = val; i2 = idx; }
            }
        }
        #pragma unroll
        for (int o = 1; o < 64; o <<= 1) {
            float ov1 = __shfl_xor(v1b, o);
            float ov2 = __shfl_xor(v2b, o);
            int   oi1 = __shfl_xor(i1, o);
            int   oi2 = __shfl_xor(i2, o);
            if (ov1 > v1b || (ov1 == v1b && oi1 < i1)) {
                float nv2; int ni2;
                if (v1b > ov2 || (v1b == ov2 && i1 < oi2)) { nv2 = v1b; ni2 = i1; }
                else { nv2 = ov2; ni2 = oi2; }
                v1b = ov1; i1 = oi1; v2b = nv2; i2 = ni2;
            } else if (ov1 > v2b || (ov1 == v2b && oi1 < i2)) {
                v2b = ov1; i2 = oi1;
            }
        }
        #pragma unroll
        for (int q = 0; q < 4; ++q) {
            float4 g1 = cent4[(size_t)i1 * 256 + q * 64 + lane];
            float4 g2 = cent4[(size_t)i2 * 256 + q * 64 + lane];
            reinterpret_cast<float4*>(out_dpcent + (size_t)row * D_N)[q * 64 + lane] = g1;
            reinterpret_cast<float4*>(out_hneg   + (size_t)row * D_N)[q * 64 + lane] = g2;
        }
        if (lane == 0) {
            out_dpidx[row] = (float)i1;
            out_hnidx[row] = (float)i2;
            out_top1[row]  = v2b;
            ws_dpidx[row]  = i1;
        }
    }
}

// ---------------------------------------------------------------------------
// Kernel 3: dp_cluster (B x B) + index_dp (K x B). grid = B_N + K_N blocks;
// fully coalesced float4 stores (1 KB/wave-instr).
// ---------------------------------------------------------------------------
__global__ __launch_bounds__(256) void kclust_kernel(
    const int* __restrict__ dpidx,
    float* __restrict__ out_cluster, float* __restrict__ out_indexdp)
{
    int bid = blockIdx.x;
    int tid = threadIdx.x;
    const int4* dpi4 = reinterpret_cast<const int4*>(dpidx);
    if (bid < B_N) {
        int i = bid;
        int me = dpidx[i];
        float* dst = out_cluster + (size_t)i * B_N;
        #pragma unroll
        for (int q = 0; q < 4; ++q) {
            int j = q * 1024 + tid * 4;
            int4 ix = dpi4[j >> 2];
            float4 v;
            v.x = (ix.x == me && (j + 0) != i) ? 1.0f : 0.0f;
            v.y = (ix.y == me && (j + 1) != i) ? 1.0f : 0.0f;
            v.z = (ix.z == me && (j + 2) != i) ? 1.0f : 0.0f;
            v.w = (ix.w == me && (j + 3) != i) ? 1.0f : 0.0f;
            *reinterpret_cast<float4*>(dst + j) = v;
        }
    } else {
        int k = bid - B_N;
        float* dst = out_indexdp + (size_t)k * B_N;
        #pragma unroll
        for (int q = 0; q < 4; ++q) {
            int j = q * 1024 + tid * 4;
            int4 ix = dpi4[j >> 2];
            float4 v;
            v.x = (ix.x == k) ? 1.0f : 0.0f;
            v.y = (ix.y == k) ? 1.0f : 0.0f;
            v.z = (ix.z == k) ? 1.0f : 0.0f;
            v.w = (ix.w == k) ? 1.0f : 0.0f;
            *reinterpret_cast<float4*>(dst + j) = v;
        }
    }
}

extern "C" void kernel_launch(void* const* d_in, const int* in_sizes, int n_in,
                              void* d_out, int out_size, void* d_ws, size_t ws_size,
                              hipStream_t stream)
{
    const float* dp   = (const float*)d_in[0];   // 4096 x 1024 f32
    const float* cent = (const float*)d_in[1];   // 256 x 1024 f32
    // d_in[2] (batch_cos_sim) is unused by the reference outputs.
    float* out = (float*)d_out;

    float* o_sims   = out;                 // 4096*256
    float* o_dpidx  = out + 1048576;       // 4096
    float* o_clust  = out + 1052672;       // 4096*4096
    float* o_idxdp  = out + 17829888;      // 256*4096
    float* o_dpcent = out + 18878464;      // 4096*1024
    float* o_hneg   = out + 23072768;      // 4096*1024
    float* o_hnidx  = out + 27267072;      // 4096
    float* o_top1   = out + 27271168;      // 4096

    char* ws = (char*)d_ws;
    ushort* phi  = (ushort*)ws;                         // 512 KiB packed hi
    ushort* plo  = (ushort*)(ws + (512u << 10));        // 512 KiB packed lo
    int*    widx = (int*)(ws + (1u << 20));             // 16 KiB

    hipLaunchKernelGGL(kcent_kernel, dim3(K_N), dim3(256), 0, stream,
                       cent, phi, plo);
    hipLaunchKernelGGL(kmain_kernel, dim3(B_N / 16), dim3(512), 0, stream,
                       dp, cent, phi, plo,
                       o_sims, o_dpidx, o_hnidx, o_top1,
                       o_dpcent, o_hneg, widx);
    hipLaunchKernelGGL(kclust_kernel, dim3(B_N + K_N), dim3(256), 0, stream,
                       widx, o_clust, o_idxdp);
}